// Round 11
// baseline (118.544 us; speedup 1.0000x reference)
//
#include <hip/hip_runtime.h>
#include <math.h>

#define N_HIST 200000
#define TOPIC 128
#define HID 128
#define KSEL 50
#define NBINS 4096           // 12-bit order-key bins (sign+8exp+3mant)
#define NBLK 512
#define NWAVE (NBLK * 4)     // 2048 waves
#define NGRP (N_HIST / 16)   // 12500 groups of 16 rows
#define NPOOL 32
#define POOL_CAP 256
#define GRU0 96              // blocks [GRU0, GRU0+96) do the GRU matvecs
#define NEG_INF (-3.402823466e38f)
// log(float32(1.0 - 1e-7)) = log(0.99999988079071045)
#define LOG_DECAY (-1.1920930e-07f)

// ws layout (4-byte words): [WS_CTRL, WS_ZEND) zeroed by a memset node.
enum { WS_CTRL  = 0,   // [1]=bar1 ticket [2]=B [3]=cHi [4]=bar1 flag [5]=bar2 ticket [8..39]=pool counts
       WS_TOT   = 64,                      // 4096
       WS_HIST2 = WS_TOT + NBINS,          // 2048 (bits 19:9 of ==B candidates)
       WS_ZEND  = WS_HIST2 + 2048,         // 6208 words = 24832 B
       WS_POOLV = WS_ZEND,                 // 8192
       WS_POOLI = WS_POOLV + NPOOL * POOL_CAP,  // 8192
       WS_GI    = WS_POOLI + NPOOL * POOL_CAP,  // 384
       WS_GH    = WS_GI + 3 * HID };            // 384

__device__ __forceinline__ unsigned keyOf(float f) {
    unsigned u = __float_as_uint(f);
    return (u & 0x80000000u) ? ~u : (u | 0x80000000u);
}

// One persistent kernel: alpha (LDS-resident) -> hist -> grid barrier (B scan,
// GRU overlapped) -> collect from LDS -> ticket -> finale on last block.
__global__ __launch_bounds__(256, 2) void fused_kernel(
        const float* __restrict__ vs, const float* __restrict__ v,
        const float* __restrict__ s_in, const float* __restrict__ t_in,
        const float* __restrict__ hs, const float* __restrict__ ts,
        const float* __restrict__ W_ih, const float* __restrict__ b_ih,
        const float* __restrict__ W_hh, const float* __restrict__ b_hh,
        const float* __restrict__ W_score, const float* __restrict__ b_score,
        unsigned* __restrict__ ctrl, unsigned* __restrict__ tot,
        unsigned* __restrict__ hist2g,
        float* __restrict__ poolV, unsigned* __restrict__ poolI,
        float* __restrict__ giW, float* __restrict__ ghW,
        float* __restrict__ out) {
    __shared__ unsigned h[NBINS / 2];      // packed 2x16-bit local histogram
    __shared__ float chunkV[7][4][16];     // this block's alpha values
    __shared__ unsigned lt[NBINS];         // B-scan staging (last block only)
    __shared__ int sLast1, sLast2;
    // finale LDS
    __shared__ unsigned pcnt[NPOOL];
    __shared__ unsigned selCnt, eqCnt, sB2, sCHi;
    __shared__ float selV[64];
    __shared__ unsigned selI[64];
    __shared__ float eqV[256];
    __shared__ unsigned eqI[256];
    __shared__ float w[64];
    __shared__ float xv[TOPIC];
    __shared__ float h0[HID];
    __shared__ float attnP[4][130];
    __shared__ float red[HID];

    const int t = threadIdx.x;
    const int wv = t >> 6, l = t & 63;
    const int blk = blockIdx.x;

    // ---- Phase A: alpha for this block's groups, kept in LDS + local hist ----
    for (int i = t; i < NBINS / 2; i += 256) h[i] = 0;
    __syncthreads();

    {
        const int half = l >> 5, c = l & 31;
        const int wave = blk * 4 + wv;
        const float4 vv = ((const float4*)v)[c];
        #pragma unroll
        for (int i = 0; i < 7; ++i) {
            const int g = wave + NWAVE * i;
            if (g < NGRP) {
                const int base = g * 16 + half * 8;
                float4 a[8];
                #pragma unroll
                for (int r = 0; r < 8; ++r)
                    a[r] = ((const float4*)vs)[(size_t)(base + r) * 32 + c];
                float s[8];
                #pragma unroll
                for (int r = 0; r < 8; ++r)
                    s[r] = a[r].x * vv.x + a[r].y * vv.y + a[r].z * vv.z + a[r].w * vv.w;
                #pragma unroll
                for (int off = 16; off; off >>= 1) {
                    #pragma unroll
                    for (int r = 0; r < 8; ++r) s[r] += __shfl_xor(s[r], off);
                }
                if (c == 0) {
                    #pragma unroll
                    for (int r = 0; r < 8; ++r) {
                        chunkV[i][wv][half * 8 + r] = s[r];
                        unsigned b = keyOf(s[r]) >> 20;
                        atomicAdd(&h[b >> 1], (b & 1u) ? 65536u : 1u);
                    }
                }
            }
        }
    }
    __syncthreads();

    // merge local hist -> global tot (nonzero halves only)
    for (int wd = t; wd < NBINS / 2; wd += 256) {
        unsigned pk = h[wd];
        unsigned lo = pk & 0xFFFFu, hi2 = pk >> 16;
        if (lo) atomicAdd(&tot[2 * wd], lo);
        if (hi2) atomicAdd(&tot[2 * wd + 1], hi2);
    }
    __threadfence();
    __syncthreads();
    if (t == 0) sLast1 = (atomicAdd(&ctrl[1], 1u) == NBLK - 1) ? 1 : 0;
    __syncthreads();

    // ---- GRU matvecs overlapped with the barrier wait ----
    if (blk >= GRU0 && blk < GRU0 + 96) {
        const int o = (blk - GRU0) * 4 + wv;
        const float* wi = W_ih + (size_t)o * (TOPIC + 1);
        float pi = wi[l] * v[l] + wi[64 + l] * v[64 + l];
        if (l == 0) pi += wi[TOPIC] * s_in[0];
        const float2 wh = ((const float2*)(W_hh + (size_t)o * HID))[l];
        const float2 hh = ((const float2*)(hs + (size_t)(N_HIST - 1) * HID))[l];
        float ph = wh.x * hh.x + wh.y * hh.y;
        #pragma unroll
        for (int off = 32; off; off >>= 1) {
            pi += __shfl_xor(pi, off);
            ph += __shfl_xor(ph, off);
        }
        if (l == 0) {
            giW[o] = pi + b_ih[o];
            ghW[o] = ph + b_hh[o];
        }
        __threadfence();
    }

    // ---- grid barrier 1: last block computes B; others spin ----
    if (sLast1) {
        __threadfence();
        for (int i = t; i < NBINS; i += 256) lt[i] = tot[i];
        __syncthreads();
        if (t < 64) {
            const int g = 63 - l;             // lane l covers group g, descending
            unsigned s = 0;
            #pragma unroll
            for (int j = 0; j < 64; ++j) s += lt[g * 64 + j];
            unsigned pre = s;
            #pragma unroll
            for (int d = 1; d <= 32; d <<= 1) {
                unsigned y = __shfl_up(pre, d);
                if (l >= d) pre += y;
            }
            unsigned long long bal = __ballot(pre >= KSEL);
            const int lstar = __ffsll(bal) - 1;
            const unsigned cumAbove = __shfl(pre - s, lstar);
            const int gstar = 63 - lstar;
            unsigned h2 = lt[gstar * 64 + (63 - l)];
            unsigned pre2 = h2;
            #pragma unroll
            for (int d = 1; d <= 32; d <<= 1) {
                unsigned y = __shfl_up(pre2, d);
                if (l >= d) pre2 += y;
            }
            unsigned long long bal2 = __ballot(cumAbove + pre2 >= KSEL);
            const int l2 = __ffsll(bal2) - 1;
            if (l == 0) ctrl[2] = (unsigned)(gstar * 64 + (63 - l2));
        }
        __syncthreads();
        if (t == 0) { __threadfence(); atomicExch(&ctrl[4], 1u); }
    } else {
        if (t == 0) {
            while (atomicAdd(&ctrl[4], 0u) == 0u) __builtin_amdgcn_s_sleep(2);
        }
    }
    __syncthreads();
    if (t == 0) sCHi = atomicAdd(&ctrl[2], 0u);   // B via atomic read
    __syncthreads();
    const unsigned B = sCHi;

    // ---- Phase B: collect from this block's LDS values ----
    #pragma unroll
    for (int rep = 0; rep < 2; ++rep) {
        const int j = t + rep * 256;
        const int i = j >> 6, wv2 = (j >> 4) & 3, r = j & 15;
        float a = 0.f;
        int g = 0;
        bool inb = (j < 448);
        if (inb) {
            g = (blk * 4 + wv2) + NWAVE * i;
            if (g < NGRP) a = chunkV[i][wv2][r];
            else inb = false;
        }
        const unsigned k = keyOf(a);
        const bool cand = inb && ((k >> 20) >= B);
        unsigned long long m = __ballot(cand);
        if (m) {
            const int pool = blk & (NPOOL - 1);
            int leader = __ffsll(m) - 1;
            unsigned basep = 0;
            if (l == leader) basep = atomicAdd(&ctrl[8 + pool], (unsigned)__popcll(m));
            basep = __shfl(basep, leader);
            if (cand) {
                unsigned pos = basep + (unsigned)__popcll(m & ((1ull << l) - 1ull));
                if (pos < POOL_CAP) {
                    poolV[pool * POOL_CAP + pos] = a;
                    poolI[pool * POOL_CAP + pos] = (unsigned)(g * 16 + r);
                }
                if ((k >> 20) > B) atomicAdd(&ctrl[3], 1u);
                else atomicAdd(&hist2g[(k >> 9) & 2047], 1u);
            }
        }
    }
    __threadfence();
    __syncthreads();
    if (t == 0) sLast2 = (atomicAdd(&ctrl[5], 1u) == NBLK - 1) ? 1 : 0;
    __syncthreads();
    if (!sLast2) return;
    __threadfence();

    // ================= finale (last block, warm CU) =================
    if (t == 0) sCHi = atomicAdd(&ctrl[3], 0u);
    __syncthreads();
    const unsigned cHi = sCHi;

    // Phase F0: wave0 = B2 scan over hist2g (2048 bins, 64x32 descending);
    //           waves1-3 stage pcnt + h0; zero counters.
    if (wv == 0) {
        const int g = 63 - l;
        const uint4* h4 = (const uint4*)(hist2g + g * 32);
        unsigned s = 0;
        #pragma unroll
        for (int j = 0; j < 8; ++j) { uint4 q = h4[j]; s += q.x + q.y + q.z + q.w; }
        unsigned pre = s;
        #pragma unroll
        for (int d = 1; d <= 32; d <<= 1) {
            unsigned y = __shfl_up(pre, d);
            if (l >= d) pre += y;
        }
        unsigned long long bal = __ballot(cHi + pre >= KSEL);
        const int lstar = __ffsll(bal) - 1;
        const unsigned cumAbove = cHi + __shfl(pre - s, lstar);
        const int gstar = 63 - lstar;
        unsigned h2 = (l < 32) ? hist2g[gstar * 32 + (31 - l)] : 0u;
        unsigned pre2 = h2;
        #pragma unroll
        for (int d = 1; d <= 16; d <<= 1) {
            unsigned y = __shfl_up(pre2, d);
            if (l >= d) pre2 += y;
        }
        unsigned long long bal2 = __ballot((l < 32) && (cumAbove + pre2 >= KSEL));
        const int l2 = __ffsll(bal2) - 1;
        if (l == 0) sB2 = (unsigned)(gstar * 32 + (31 - l2));
    } else {
        if (t >= 64 && t < 96) pcnt[t - 64] = min(ctrl[8 + (t - 64)], (unsigned)POOL_CAP);
        if (t == 96) { selCnt = 0; eqCnt = 0; }
        if (t >= 128 && t < 256) h0[t - 128] = hs[(size_t)(N_HIST - 1) * HID + (t - 128)];
    }
    __syncthreads();
    const unsigned B2 = sB2;

    // Phase F1: filter candidates (8 threads/pool, actual counts only).
    {
        const int p = t >> 3, i0 = t & 7;
        const int cnt = (int)pcnt[p];
        for (int i = i0; i < cnt; i += 8) {
            float a = poolV[p * POOL_CAP + i];
            unsigned k = keyOf(a);
            unsigned top = k >> 20, sub = (k >> 9) & 2047;
            bool hi = (top > B) || (top == B && sub > B2);
            bool eq = (top == B) && (sub == B2);
            if (hi) {
                unsigned pos = atomicAdd(&selCnt, 1u);
                if (pos < 64u) { selV[pos] = a; selI[pos] = poolI[p * POOL_CAP + i]; }
            } else if (eq) {
                unsigned pos = atomicAdd(&eqCnt, 1u);
                if (pos < 256u) { eqV[pos] = a; eqI[pos] = poolI[p * POOL_CAP + i]; }
            }
        }
    }
    __syncthreads();

    const int Scnt = min((int)selCnt, 64);      // < KSEL by B2 construction
    const int eqN = min((int)eqCnt, 256);
    int need = KSEL - Scnt;
    if (need < 0) need = 0;
    if (need > eqN) need = eqN;
    const int S = Scnt + need;

    // Phase F2: wave0 = exact rank of tiny tie pool; others stage xv.
    if (wv == 0) {
        if (need > 0) {
            for (int c = l; c < eqN; c += 64) {
                const float mv = eqV[c];
                const unsigned mi = eqI[c];
                int r = 0;
                for (int j = 0; j < eqN; ++j) {
                    const float vj = eqV[j];
                    const unsigned ij = eqI[j];
                    r += (int)((vj > mv) | ((vj == mv) & (ij < mi)));
                }
                if (r < need) { selV[Scnt + r] = mv; selI[Scnt + r] = mi; }
            }
        }
    } else if (t >= 128 && t < 256) {
        xv[t - 128] = v[t - 128];
    }
    __syncthreads();

    // Phase F3: all waves issue attn hs gathers (overlaps wave0 softmax).
    unsigned ridx[13];
    float2 hv[13];
    #pragma unroll
    for (int j = 0; j < 13; ++j) {
        const int k = wv + 4 * j;
        ridx[j] = (k < S) ? selI[k] : 0u;
    }
    #pragma unroll
    for (int j = 0; j < 13; ++j)
        hv[j] = ((const float2*)(hs + (size_t)ridx[j] * HID))[l];

    if (wv == 0) {
        const float tt = t_in[0];
        float dv = NEG_INF;
        if (l < S) dv = selV[l] * expf((tt - ts[selI[l]]) * LOG_DECAY);
        float m = dv;
        #pragma unroll
        for (int o = 32; o; o >>= 1) m = fmaxf(m, __shfl_xor(m, o));
        float e = (l < S) ? expf(dv - m) : 0.f;
        float sum = e;
        #pragma unroll
        for (int o = 32; o; o >>= 1) sum += __shfl_xor(sum, o);
        if (l < S) w[l] = e / sum;
    }
    __syncthreads();

    // Phase F4: weighted accumulate + attnP write.
    {
        float2 acc = make_float2(0.f, 0.f);
        #pragma unroll
        for (int j = 0; j < 13; ++j) {
            const int k = wv + 4 * j;
            const float wk = (k < S) ? w[k] : 0.f;
            acc.x += wk * hv[j].x; acc.y += wk * hv[j].y;
        }
        attnP[wv][2 * l]     = acc.x;
        attnP[wv][2 * l + 1] = acc.y;
    }
    __syncthreads();

    // Phase F5: score partial + GRU gates.
    if (t < HID) {
        float ah = attnP[0][t] + attnP[1][t] + attnP[2][t] + attnP[3][t];
        red[t] = xv[t] * W_score[t] + ah * W_score[HID + t];
        const float r = 1.f / (1.f + expf(-(giW[t] + ghW[t])));
        const float z = 1.f / (1.f + expf(-(giW[HID + t] + ghW[HID + t])));
        const float n = tanhf(giW[2 * HID + t] + r * ghW[2 * HID + t]);
        out[1 + t] = (1.f - z) * n + z * h0[t];
    }
    __syncthreads();

    if (t < 64) {
        float sv = red[t] + red[64 + t];
        #pragma unroll
        for (int o = 32; o; o >>= 1) sv += __shfl_xor(sv, o);
        if (t == 0) out[0] = sv + b_score[0];
    }
}

extern "C" void kernel_launch(void* const* d_in, const int* in_sizes, int n_in,
                              void* d_out, int out_size, void* d_ws, size_t ws_size,
                              hipStream_t stream) {
    const float* v       = (const float*)d_in[0];
    const float* s_in    = (const float*)d_in[1];
    const float* t_in    = (const float*)d_in[2];
    const float* vs      = (const float*)d_in[3];
    const float* hs      = (const float*)d_in[4];
    const float* ts      = (const float*)d_in[5];
    const float* W_ih    = (const float*)d_in[6];
    const float* b_ih    = (const float*)d_in[7];
    const float* W_hh    = (const float*)d_in[8];
    const float* b_hh    = (const float*)d_in[9];
    const float* W_score = (const float*)d_in[10];
    const float* b_score = (const float*)d_in[11];
    float* out = (float*)d_out;

    unsigned* ws     = (unsigned*)d_ws;
    unsigned* ctrl   = ws + WS_CTRL;
    unsigned* tot    = ws + WS_TOT;
    unsigned* hist2g = ws + WS_HIST2;
    float*    poolV  = (float*)(ws + WS_POOLV);
    unsigned* poolI  = ws + WS_POOLI;
    float*    giW    = (float*)(ws + WS_GI);
    float*    ghW    = (float*)(ws + WS_GH);

    hipMemsetAsync(ws, 0, (size_t)WS_ZEND * 4, stream);
    fused_kernel<<<NBLK, 256, 0, stream>>>(vs, v, s_in, t_in, hs, ts,
                                           W_ih, b_ih, W_hh, b_hh, W_score, b_score,
                                           ctrl, tot, hist2g, poolV, poolI,
                                           giW, ghW, out);
}

// Round 12
// 71.990 us; speedup vs baseline: 1.6467x; 1.6467x over previous
//
#include <hip/hip_runtime.h>
#include <math.h>

#define N_HIST 200000
#define TOPIC 128
#define HID 128
#define KSEL 50
#define NBINS 4096           // 12-bit order-key bins (sign+8exp+3mant)
#define NFB 196              // fused blocks (<=256 CUs -> co-resident)
#define PER_BLK 1024         // alpha slice per fused block
#define NPOOL 32
#define POOL_CAP 1024        // >= per-block max candidates -> no silent drop
#define GRU0 64              // blocks [GRU0, GRU0+96) do GRU matvecs
#define NEG_INF (-3.402823466e38f)
// log(float32(1.0 - 1e-7)) = log(0.99999988079071045)
#define LOG_DECAY (-1.1920930e-07f)

// ws layout (4-byte words): [0, WS_ZEND) zeroed by alpha_kernel's first blocks.
enum { WS_CTRL  = 0,   // [1]=ticket1 [2]=B [3]=cHi [4]=flag [5]=ticket2 [8..39]=pool counts
       WS_TOT   = 64,                       // 4096
       WS_HIST2 = WS_TOT + NBINS,           // 2048 (bits 19:9 of ==B candidates)
       WS_ZEND  = WS_HIST2 + 2048,          // 6208
       WS_ALPHA = WS_ZEND,                  // 200000
       WS_POOLV = WS_ALPHA + N_HIST,        // 32768
       WS_POOLI = WS_POOLV + NPOOL * POOL_CAP,   // 32768
       WS_GI    = WS_POOLI + NPOOL * POOL_CAP,   // 384
       WS_GH    = WS_GI + 3 * HID };             // 384

__device__ __forceinline__ unsigned keyOf(float f) {
    unsigned u = __float_as_uint(f);
    return (u & 0x80000000u) ? ~u : (u | 0x80000000u);
}

// Kernel 1: alpha[i] = dot(vs[i], v); first 25 blocks also zero ctrl+tot+hist2.
// 3125 blocks -> full memory-level parallelism for the 102 MB stream.
__global__ __launch_bounds__(256) void alpha_kernel(
        const float* __restrict__ vs, const float* __restrict__ v,
        float* __restrict__ alpha, unsigned* __restrict__ wsbase) {
    const int zi = blockIdx.x * 256 + threadIdx.x;
    if (zi < WS_ZEND) wsbase[zi] = 0;
    const int lane = threadIdx.x & 63;
    const int wave = (blockIdx.x * blockDim.x + threadIdx.x) >> 6;
    const int half = lane >> 5;
    const int c = lane & 31;
    const int base = wave * 16 + half * 8;
    const float4 vv = ((const float4*)v)[c];
    float4 a[8];
    #pragma unroll
    for (int r = 0; r < 8; ++r)
        a[r] = ((const float4*)vs)[(size_t)(base + r) * 32 + c];
    float s[8];
    #pragma unroll
    for (int r = 0; r < 8; ++r)
        s[r] = a[r].x * vv.x + a[r].y * vv.y + a[r].z * vv.z + a[r].w * vv.w;
    #pragma unroll
    for (int off = 16; off; off >>= 1) {
        #pragma unroll
        for (int r = 0; r < 8; ++r) s[r] += __shfl_xor(s[r], off);
    }
    if (c == 0) {
        float4* dst = (float4*)(alpha + base);
        dst[0] = make_float4(s[0], s[1], s[2], s[3]);
        dst[1] = make_float4(s[4], s[5], s[6], s[7]);
    }
}

// Kernel 2 (196 blocks, co-resident): hist from LDS-staged alpha slice ->
// grid barrier (B scan on last block, GRU overlapped) -> collect from LDS ->
// ticket -> finale on last block.
__global__ __launch_bounds__(256) void fused2_kernel(
        const float* __restrict__ alpha,
        unsigned* __restrict__ ctrl, unsigned* __restrict__ tot,
        unsigned* __restrict__ hist2g,
        float* __restrict__ poolV, unsigned* __restrict__ poolI,
        const float* __restrict__ v, const float* __restrict__ s_in,
        const float* __restrict__ t_in,
        const float* __restrict__ hs, const float* __restrict__ ts,
        const float* __restrict__ W_ih, const float* __restrict__ b_ih,
        const float* __restrict__ W_hh, const float* __restrict__ b_hh,
        const float* __restrict__ W_score, const float* __restrict__ b_score,
        float* __restrict__ giW, float* __restrict__ ghW,
        float* __restrict__ out) {
    __shared__ unsigned h[NBINS / 2];      // packed 2x16-bit local histogram
    __shared__ float chunk[PER_BLK];       // this block's alpha slice
    __shared__ unsigned lt[NBINS];         // B-scan staging (last block only)
    __shared__ int sLast1, sLast2;
    __shared__ unsigned pcnt[NPOOL];
    __shared__ unsigned selCnt, eqCnt, sB2, sTmp;
    __shared__ float selV[64];
    __shared__ unsigned selI[64];
    __shared__ float eqV[256];
    __shared__ unsigned eqI[256];
    __shared__ float w[64];
    __shared__ float xv[TOPIC];
    __shared__ float h0[HID];
    __shared__ float attnP[4][130];
    __shared__ float red[HID];

    const int t = threadIdx.x;
    const int wv = t >> 6, l = t & 63;
    const int blk = blockIdx.x;
    const int base = blk * PER_BLK;

    // ---- Phase H: stage slice in LDS + private histogram ----
    for (int i = t; i < NBINS / 2; i += 256) h[i] = 0;
    __syncthreads();
    #pragma unroll
    for (int j = 0; j < 4; ++j) {
        const int idx = base + t + 256 * j;
        float a = 0.f;
        if (idx < N_HIST) {
            a = alpha[idx];
            unsigned b = keyOf(a) >> 20;
            atomicAdd(&h[b >> 1], (b & 1u) ? 65536u : 1u);
        }
        chunk[t + 256 * j] = a;
    }
    __syncthreads();
    for (int wd = t; wd < NBINS / 2; wd += 256) {
        unsigned pk = h[wd];
        unsigned lo = pk & 0xFFFFu, hi2 = pk >> 16;
        if (lo) atomicAdd(&tot[2 * wd], lo);
        if (hi2) atomicAdd(&tot[2 * wd + 1], hi2);
    }
    __threadfence();
    __syncthreads();
    if (t == 0) sLast1 = (atomicAdd(&ctrl[1], 1u) == NFB - 1) ? 1 : 0;
    __syncthreads();

    // ---- GRU matvecs overlapped with barrier wait ----
    if (blk >= GRU0 && blk < GRU0 + 96) {
        const int o = (blk - GRU0) * 4 + wv;
        const float* wi = W_ih + (size_t)o * (TOPIC + 1);
        float pi = wi[l] * v[l] + wi[64 + l] * v[64 + l];
        if (l == 0) pi += wi[TOPIC] * s_in[0];
        const float2 wh = ((const float2*)(W_hh + (size_t)o * HID))[l];
        const float2 hh = ((const float2*)(hs + (size_t)(N_HIST - 1) * HID))[l];
        float ph = wh.x * hh.x + wh.y * hh.y;
        #pragma unroll
        for (int off = 32; off; off >>= 1) {
            pi += __shfl_xor(pi, off);
            ph += __shfl_xor(ph, off);
        }
        if (l == 0) {
            giW[o] = pi + b_ih[o];
            ghW[o] = ph + b_hh[o];
        }
        __threadfence();
    }

    // ---- grid barrier: last block computes B; others spin ----
    if (sLast1) {
        __threadfence();
        for (int i = t; i < NBINS; i += 256) lt[i] = tot[i];
        __syncthreads();
        if (t < 64) {
            const int g = 63 - l;             // lane l covers group g, descending
            unsigned s = 0;
            #pragma unroll
            for (int j = 0; j < 64; ++j) s += lt[g * 64 + j];
            unsigned pre = s;
            #pragma unroll
            for (int d = 1; d <= 32; d <<= 1) {
                unsigned y = __shfl_up(pre, d);
                if (l >= d) pre += y;
            }
            unsigned long long bal = __ballot(pre >= KSEL);
            const int lstar = __ffsll(bal) - 1;
            const unsigned cumAbove = __shfl(pre - s, lstar);
            const int gstar = 63 - lstar;
            unsigned h2 = lt[gstar * 64 + (63 - l)];
            unsigned pre2 = h2;
            #pragma unroll
            for (int d = 1; d <= 32; d <<= 1) {
                unsigned y = __shfl_up(pre2, d);
                if (l >= d) pre2 += y;
            }
            unsigned long long bal2 = __ballot(cumAbove + pre2 >= KSEL);
            const int l2 = __ffsll(bal2) - 1;
            if (l == 0) ctrl[2] = (unsigned)(gstar * 64 + (63 - l2));
        }
        __syncthreads();
        if (t == 0) { __threadfence(); atomicExch(&ctrl[4], 1u); }
    } else {
        if (t == 0) {
            while (atomicAdd(&ctrl[4], 0u) == 0u) __builtin_amdgcn_s_sleep(2);
        }
    }
    __syncthreads();
    if (t == 0) sTmp = atomicAdd(&ctrl[2], 0u);
    __syncthreads();
    const unsigned B = sTmp;

    // ---- Phase C: collect from LDS slice ----
    const int pool = blk & (NPOOL - 1);
    #pragma unroll
    for (int j = 0; j < 4; ++j) {
        const int tt2 = t + 256 * j;
        const int idx = base + tt2;
        const float a = chunk[tt2];
        const unsigned k = keyOf(a);
        const bool cand = (idx < N_HIST) && ((k >> 20) >= B);
        unsigned long long m = __ballot(cand);
        if (m) {
            int leader = __ffsll(m) - 1;
            unsigned basep = 0;
            if (l == leader) basep = atomicAdd(&ctrl[8 + pool], (unsigned)__popcll(m));
            basep = __shfl(basep, leader);
            if (cand) {
                unsigned pos = basep + (unsigned)__popcll(m & ((1ull << l) - 1ull));
                if (pos < POOL_CAP) {
                    poolV[pool * POOL_CAP + pos] = a;
                    poolI[pool * POOL_CAP + pos] = (unsigned)idx;
                }
                if ((k >> 20) > B) atomicAdd(&ctrl[3], 1u);
                else atomicAdd(&hist2g[(k >> 9) & 2047], 1u);
            }
        }
    }
    __threadfence();
    __syncthreads();
    if (t == 0) sLast2 = (atomicAdd(&ctrl[5], 1u) == NFB - 1) ? 1 : 0;
    __syncthreads();
    if (!sLast2) return;
    __threadfence();

    // ================= finale (last block, warm CU) =================
    if (t == 0) sTmp = atomicAdd(&ctrl[3], 0u);
    __syncthreads();
    const unsigned cHi = sTmp;

    // Phase F0: wave0 = B2 scan over hist2g; waves1-3 stage pcnt + h0.
    if (wv == 0) {
        const int g = 63 - l;
        const uint4* h4 = (const uint4*)(hist2g + g * 32);
        unsigned s = 0;
        #pragma unroll
        for (int j = 0; j < 8; ++j) { uint4 q = h4[j]; s += q.x + q.y + q.z + q.w; }
        unsigned pre = s;
        #pragma unroll
        for (int d = 1; d <= 32; d <<= 1) {
            unsigned y = __shfl_up(pre, d);
            if (l >= d) pre += y;
        }
        unsigned long long bal = __ballot(cHi + pre >= KSEL);
        const int lstar = __ffsll(bal) - 1;
        const unsigned cumAbove = cHi + __shfl(pre - s, lstar);
        const int gstar = 63 - lstar;
        unsigned h2 = (l < 32) ? hist2g[gstar * 32 + (31 - l)] : 0u;
        unsigned pre2 = h2;
        #pragma unroll
        for (int d = 1; d <= 16; d <<= 1) {
            unsigned y = __shfl_up(pre2, d);
            if (l >= d) pre2 += y;
        }
        unsigned long long bal2 = __ballot((l < 32) && (cumAbove + pre2 >= KSEL));
        const int l2 = __ffsll(bal2) - 1;
        if (l == 0) sB2 = (unsigned)(gstar * 32 + (31 - l2));
    } else {
        if (t >= 64 && t < 96) pcnt[t - 64] = min(ctrl[8 + (t - 64)], (unsigned)POOL_CAP);
        if (t == 96) { selCnt = 0; eqCnt = 0; }
        if (t >= 128 && t < 256) h0[t - 128] = hs[(size_t)(N_HIST - 1) * HID + (t - 128)];
    }
    __syncthreads();
    const unsigned B2 = sB2;

    // Phase F1: filter candidates (8 threads/pool, actual counts only).
    {
        const int p = t >> 3, i0 = t & 7;
        const int cnt = (int)pcnt[p];
        for (int i = i0; i < cnt; i += 8) {
            float a = poolV[p * POOL_CAP + i];
            unsigned k = keyOf(a);
            unsigned top = k >> 20, sub = (k >> 9) & 2047;
            bool hi = (top > B) || (top == B && sub > B2);
            bool eq = (top == B) && (sub == B2);
            if (hi) {
                unsigned pos = atomicAdd(&selCnt, 1u);
                if (pos < 64u) { selV[pos] = a; selI[pos] = poolI[p * POOL_CAP + i]; }
            } else if (eq) {
                unsigned pos = atomicAdd(&eqCnt, 1u);
                if (pos < 256u) { eqV[pos] = a; eqI[pos] = poolI[p * POOL_CAP + i]; }
            }
        }
    }
    __syncthreads();

    const int Scnt = min((int)selCnt, 64);      // < KSEL by B2 construction
    const int eqN = min((int)eqCnt, 256);
    int need = KSEL - Scnt;
    if (need < 0) need = 0;
    if (need > eqN) need = eqN;
    const int S = Scnt + need;

    // Phase F2: wave0 = exact rank of tiny tie pool; others stage xv.
    if (wv == 0) {
        if (need > 0) {
            for (int c = l; c < eqN; c += 64) {
                const float mv = eqV[c];
                const unsigned mi = eqI[c];
                int r = 0;
                for (int j = 0; j < eqN; ++j) {
                    const float vj = eqV[j];
                    const unsigned ij = eqI[j];
                    r += (int)((vj > mv) | ((vj == mv) & (ij < mi)));
                }
                if (r < need) { selV[Scnt + r] = mv; selI[Scnt + r] = mi; }
            }
        }
    } else if (t >= 128 && t < 256) {
        xv[t - 128] = v[t - 128];
    }
    __syncthreads();

    // Phase F3: all waves issue attn hs gathers (overlaps wave0 softmax).
    unsigned ridx[13];
    float2 hv[13];
    #pragma unroll
    for (int j = 0; j < 13; ++j) {
        const int k = wv + 4 * j;
        ridx[j] = (k < S) ? selI[k] : 0u;
    }
    #pragma unroll
    for (int j = 0; j < 13; ++j)
        hv[j] = ((const float2*)(hs + (size_t)ridx[j] * HID))[l];

    if (wv == 0) {
        const float tt = t_in[0];
        float dv = NEG_INF;
        if (l < S) dv = selV[l] * expf((tt - ts[selI[l]]) * LOG_DECAY);
        float m = dv;
        #pragma unroll
        for (int o = 32; o; o >>= 1) m = fmaxf(m, __shfl_xor(m, o));
        float e = (l < S) ? expf(dv - m) : 0.f;
        float sum = e;
        #pragma unroll
        for (int o = 32; o; o >>= 1) sum += __shfl_xor(sum, o);
        if (l < S) w[l] = e / sum;
    }
    __syncthreads();

    // Phase F4: weighted accumulate + attnP write.
    {
        float2 acc = make_float2(0.f, 0.f);
        #pragma unroll
        for (int j = 0; j < 13; ++j) {
            const int k = wv + 4 * j;
            const float wk = (k < S) ? w[k] : 0.f;
            acc.x += wk * hv[j].x; acc.y += wk * hv[j].y;
        }
        attnP[wv][2 * l]     = acc.x;
        attnP[wv][2 * l + 1] = acc.y;
    }
    __syncthreads();

    // Phase F5: score partial + GRU gates.
    if (t < HID) {
        float ah = attnP[0][t] + attnP[1][t] + attnP[2][t] + attnP[3][t];
        red[t] = xv[t] * W_score[t] + ah * W_score[HID + t];
        const float r = 1.f / (1.f + expf(-(giW[t] + ghW[t])));
        const float z = 1.f / (1.f + expf(-(giW[HID + t] + ghW[HID + t])));
        const float n = tanhf(giW[2 * HID + t] + r * ghW[2 * HID + t]);
        out[1 + t] = (1.f - z) * n + z * h0[t];
    }
    __syncthreads();

    if (t < 64) {
        float sv = red[t] + red[64 + t];
        #pragma unroll
        for (int o = 32; o; o >>= 1) sv += __shfl_xor(sv, o);
        if (t == 0) out[0] = sv + b_score[0];
    }
}

extern "C" void kernel_launch(void* const* d_in, const int* in_sizes, int n_in,
                              void* d_out, int out_size, void* d_ws, size_t ws_size,
                              hipStream_t stream) {
    const float* v       = (const float*)d_in[0];
    const float* s_in    = (const float*)d_in[1];
    const float* t_in    = (const float*)d_in[2];
    const float* vs      = (const float*)d_in[3];
    const float* hs      = (const float*)d_in[4];
    const float* ts      = (const float*)d_in[5];
    const float* W_ih    = (const float*)d_in[6];
    const float* b_ih    = (const float*)d_in[7];
    const float* W_hh    = (const float*)d_in[8];
    const float* b_hh    = (const float*)d_in[9];
    const float* W_score = (const float*)d_in[10];
    const float* b_score = (const float*)d_in[11];
    float* out = (float*)d_out;

    unsigned* ws     = (unsigned*)d_ws;
    unsigned* ctrl   = ws + WS_CTRL;
    unsigned* tot    = ws + WS_TOT;
    unsigned* hist2g = ws + WS_HIST2;
    float*    alpha  = (float*)(ws + WS_ALPHA);
    float*    poolV  = (float*)(ws + WS_POOLV);
    unsigned* poolI  = ws + WS_POOLI;
    float*    giW    = (float*)(ws + WS_GI);
    float*    ghW    = (float*)(ws + WS_GH);

    alpha_kernel<<<3125, 256, 0, stream>>>(vs, v, alpha, ws);
    fused2_kernel<<<NFB, 256, 0, stream>>>(alpha, ctrl, tot, hist2g, poolV, poolI,
                                           v, s_in, t_in, hs, ts,
                                           W_ih, b_ih, W_hh, b_hh, W_score, b_score,
                                           giW, ghW, out);
}